// Round 15
// baseline (362.430 us; speedup 1.0000x reference)
//
#include <hip/hip_runtime.h>
#include <hip/hip_bf16.h>
#include <stdint.h>

typedef short bf16x8 __attribute__((ext_vector_type(8)));   // 8 bf16 in 4 VGPRs
typedef float f32x4 __attribute__((ext_vector_type(4)));
typedef unsigned short u16;
typedef u16 u16x8 __attribute__((ext_vector_type(8)));

__device__ __forceinline__ u16 f2bf(float x) {
  __hip_bfloat16 h = __float2bfloat16(x);
  return *reinterpret_cast<u16*>(&h);
}
__device__ __forceinline__ float bf2f(u16 v) {
  unsigned u = (unsigned)v << 16;
  return *reinterpret_cast<float*>(&u);
}

// async global->LDS, 16B per lane. LDS dest is wave-uniform base + lane*16 (m104/m108).
__device__ __forceinline__ void gload_lds16(const void* g, const void* lds_base) {
  __builtin_amdgcn_global_load_lds(
      (const __attribute__((address_space(1))) unsigned int*)(uintptr_t)g,
      (__attribute__((address_space(3))) unsigned int*)(uintptr_t)lds_base,
      16, 0, 0);
}

#define BAR() __builtin_amdgcn_s_barrier()

// ---------------- LayerNorm + cast to bf16 (rows of q,k,v), float4-vectorized ----------------
__global__ __launch_bounds__(256) void ln_cast_kernel(
    const float* __restrict__ q, const float* __restrict__ k, const float* __restrict__ v,
    const float* __restrict__ lw, const float* __restrict__ lb, u16* __restrict__ out) {
  int row = blockIdx.x;
  const float* x;
  if (row < 8192) x = q + (size_t)row * 768;
  else if (row < 16384) x = k + (size_t)(row - 8192) * 768;
  else x = v + (size_t)(row - 16384) * 768;
  int t = threadIdx.x;
  __shared__ float red[4];
  __shared__ float red2[4];
  float4 a = (t < 192) ? ((const float4*)x)[t] : make_float4(0.f, 0.f, 0.f, 0.f);
  float s = a.x + a.y + a.z + a.w;
  for (int o = 32; o; o >>= 1) s += __shfl_down(s, o, 64);
  if ((t & 63) == 0) red[t >> 6] = s;
  __syncthreads();
  float mean = (red[0] + red[1] + red[2]) * (1.0f / 768.0f);
  float4 d = make_float4(a.x - mean, a.y - mean, a.z - mean, a.w - mean);
  float vs = (t < 192) ? (d.x * d.x + d.y * d.y + d.z * d.z + d.w * d.w) : 0.f;
  for (int o = 32; o; o >>= 1) vs += __shfl_down(vs, o, 64);
  if ((t & 63) == 0) red2[t >> 6] = vs;
  __syncthreads();
  float var = (red2[0] + red2[1] + red2[2]) * (1.0f / 768.0f);
  float rstd = rsqrtf(var + 1e-5f);
  if (t < 192) {
    float4 wv = ((const float4*)lw)[t];
    float4 bv = ((const float4*)lb)[t];
    ushort4 o;
    o.x = f2bf(d.x * rstd * wv.x + bv.x);
    o.y = f2bf(d.y * rstd * wv.y + bv.y);
    o.z = f2bf(d.z * rstd * wv.z + bv.z);
    o.w = f2bf(d.w * rstd * wv.w + bv.w);
    ((ushort4*)(out + (size_t)row * 768))[t] = o;
  }
}

// ---------------- both weight casts in one launch ----------------
__global__ __launch_bounds__(256) void cast2_f32_bf16(
    const float* __restrict__ wa, const float* __restrict__ wb,
    u16* __restrict__ oa, u16* __restrict__ ob) {
  int i = blockIdx.x * 256 + threadIdx.x;
  const float* in = (i < 147456) ? wa : wb;
  u16* out = (i < 147456) ? oa : ob;
  int j = (i < 147456) ? i : i - 147456;
  float4 vv = ((const float4*)in)[j];
  ushort4 o;
  o.x = f2bf(vv.x); o.y = f2bf(vv.y); o.z = f2bf(vv.z); o.w = f2bf(vv.w);
  ((ushort4*)out)[j] = o;
}

// ---------------- zero fp32 buffer ----------------
__global__ __launch_bounds__(256) void zero_f32(float* __restrict__ p, int n) {
  int i = blockIdx.x * 256 + threadIdx.x;
  if (i < n) p[i] = 0.0f;
}

// ---------------- sum 4 bf16 partials, scale by 1/rowsum, write bf16 ----------------
__global__ __launch_bounds__(256) void reduce4_scale(
    const u16* __restrict__ p0, const u16* __restrict__ p1,
    const u16* __restrict__ p2, const u16* __restrict__ p3,
    const float* __restrict__ rowsum, u16* __restrict__ out, int n8) {
  int i = blockIdx.x * 256 + threadIdx.x;
  if (i < n8) {
    float inv = 1.0f / rowsum[i / 96];
    u16x8 a = ((const u16x8*)p0)[i];
    u16x8 b = ((const u16x8*)p1)[i];
    u16x8 c = ((const u16x8*)p2)[i];
    u16x8 d = ((const u16x8*)p3)[i];
    u16x8 o;
#pragma unroll
    for (int j = 0; j < 8; j++)
      o[j] = f2bf((bf2f(a[j]) + bf2f(b[j]) + bf2f(c[j]) + bf2f(d[j])) * inv);
    ((u16x8*)out)[i] = o;
  }
}

// ========== unified fast bt-GEMM: 128x128 tile, BK=32, 4-rot, stage-ahead-3, vmcnt(8) ==========
// Round-12/13-proven schedule (single barrier/phase, counted vmcnt, involution swizzle,
// 64KB LDS -> 2 blocks/CU). 256 thr = 4 waves (2x2 of 64x64). Runtime nk = K/32.
// MODE 0: PV partial — K-offset z*2048, C = partial bufs, bf16 out
// MODE 1: QK — C = exp(acc*scale) bf16 (ldc 8192) + per-row sums atomically into rowsum;
//         per-XCD 4-tm-stripe mapping (B-panel reused 4x, ~1.2MB L2 working set)
// MODE 2: f32 out + bias[col]
// MODE 3: qkv — tiles tm>=128 (vn rows) write TRANSPOSED into C1 as vnT[col][row-16384]
template <int MODE>
__global__ __launch_bounds__(256, 2) void gemm_fast(
    const u16* __restrict__ A, const u16* __restrict__ B,
    u16* __restrict__ C0, u16* __restrict__ C1,
    int lda, int ldb, int ldc, int nk, int nTn, int cpx,
    const float* __restrict__ bias, float scale, float* __restrict__ rowsum) {
  __shared__ __align__(16) u16 lds[4 * 8192];  // 64 KB: A bufs 0-3 (32KB) | B bufs 0-3 (32KB)
  const int z = blockIdx.y;
  const int koff = (MODE == 0) ? (z << 11) : 0;
  u16* C = C0;
  if (MODE == 0) C = (z < 2) ? C0 + (size_t)z * 6291456 : C1 + (size_t)(z - 2) * 6291456;
  int orig = blockIdx.x;                       // gridDim.x % 8 == 0
  int tm, tn;
  if (MODE == 1) {
    // 4096 blocks: xcd owns tm in [xcd*8, xcd*8+8), two stripes of 4 tm, tn sweeps per stripe
    int i = orig >> 3, xcd = orig & 7;
    tn = (i & 255) >> 2;
    tm = xcd * 8 + ((i >> 8) << 2) + (i & 3);
  } else {
    int wg = (orig & 7) * cpx + (orig >> 3);
    tm = wg / nTn; tn = wg % nTn;
  }
  const int t = threadIdx.x, l = t & 63, w = t >> 6;
  const int wr = w >> 1, wc = w & 1;           // 2 x 2 wave grid
  const int lr = l & 15, lq = l >> 4;
  const int colb = lq * 16;

  f32x4 acc[4][4];
#pragma unroll
  for (int m = 0; m < 4; m++)
#pragma unroll
    for (int n = 0; n < 4; n++) acc[m][n] = (f32x4){0.f, 0.f, 0.f, 0.f};

  const size_t rA0 = (size_t)tm * 128, rB0 = (size_t)tn * 128;

  // hoisted addressing (idx: 0,1 = A row-halves; 2,3 = B row-halves)
  const char* gsrc[4];
  int ldsoff[4];
#pragma unroll
  for (int idx = 0; idx < 4; idx++) {
    const u16* src = (idx < 2) ? A : B;
    size_t r0 = (idx < 2) ? rA0 : rB0;
    int ld = (idx < 2) ? lda : ldb;
    int p = idx & 1;
    int x = p * 4096 + t * 16;                  // byte offset in 8KB half
    int r = x >> 6;                             // row 0..127
    int cb = (x & 63) ^ (((r >> 1) & 3) << 4);  // pre-swizzled source byte col
    gsrc[idx] = (const char*)(src + (r0 + r) * (size_t)ld + koff) + cb;
    ldsoff[idx] = ((idx < 2) ? 0 : 32768) + p * 4096 + w * 1024;
  }
  int offA[4], offB[4];
#pragma unroll
  for (int mf = 0; mf < 4; mf++) {
    int row = wr * 64 + mf * 16 + lr;
    int x = row * 64 + colb;
    offA[mf] = x ^ (((row >> 1) & 3) << 4);
  }
#pragma unroll
  for (int nf = 0; nf < 4; nf++) {
    int row = wc * 64 + nf * 16 + lr;
    int x = row * 64 + colb;
    offB[nf] = 32768 + (x ^ (((row >> 1) & 3) << 4));
  }

#define GSCALL(BUF, TT, IDX)                                                 \
  gload_lds16(gsrc[IDX] + (size_t)(TT) * 64,                                 \
              (const char*)lds + (BUF) * 8192 + ldsoff[IDX])

  // prologue: stage tiles 0,1,2; wait tile 0 (8 in flight); barrier
  GSCALL(0, 0, 0); GSCALL(0, 0, 1); GSCALL(0, 0, 2); GSCALL(0, 0, 3);
  GSCALL(1, 1, 0); GSCALL(1, 1, 1); GSCALL(1, 1, 2); GSCALL(1, 1, 3);
  GSCALL(2, 2, 0); GSCALL(2, 2, 1); GSCALL(2, 2, 2); GSCALL(2, 2, 3);
  asm volatile("s_waitcnt vmcnt(8)" ::: "memory");
  BAR();

  for (int T = 0; T < nk; T++) {
    const int cur = T & 3;
    bf16x8 aF[4], bF[4];
#pragma unroll
    for (int mf = 0; mf < 4; mf++)
      aF[mf] = *(const bf16x8*)((const char*)lds + cur * 8192 + offA[mf]);
#pragma unroll
    for (int nf = 0; nf < 4; nf++)
      bF[nf] = *(const bf16x8*)((const char*)lds + cur * 8192 + offB[nf]);
    if (T + 3 < nk) {
      const int nb = (T + 3) & 3;
      GSCALL(nb, T + 3, 0); GSCALL(nb, T + 3, 1);
      GSCALL(nb, T + 3, 2); GSCALL(nb, T + 3, 3);
    }
    __builtin_amdgcn_s_setprio(1);
#pragma unroll
    for (int mf = 0; mf < 4; mf++)
#pragma unroll
      for (int nf = 0; nf < 4; nf++)
        acc[mf][nf] = __builtin_amdgcn_mfma_f32_16x16x32_bf16(
            aF[mf], bF[nf], acc[mf][nf], 0, 0, 0);
    __builtin_amdgcn_s_setprio(0);
    if (T < nk - 3)       asm volatile("s_waitcnt vmcnt(8)" ::: "memory");
    else if (T == nk - 3) asm volatile("s_waitcnt vmcnt(4)" ::: "memory");
    else if (T == nk - 2) asm volatile("s_waitcnt vmcnt(0)" ::: "memory");
    BAR();
  }
#undef GSCALL

  // epilogue (C/D layout col=lane&15, row=(lane>>4)*4+j)
  if (MODE == 1) {
    float rs[4][4];
#pragma unroll
    for (int mf = 0; mf < 4; mf++)
#pragma unroll
      for (int j = 0; j < 4; j++) rs[mf][j] = 0.0f;
#pragma unroll
    for (int mf = 0; mf < 4; mf++) {
      int row = tm * 128 + wr * 64 + mf * 16 + lq * 4;
#pragma unroll
      for (int nf = 0; nf < 4; nf++) {
        int col = tn * 128 + wc * 64 + nf * 16 + lr;
#pragma unroll
        for (int j = 0; j < 4; j++) {
          float e = __expf(acc[mf][nf][j] * scale);
          C0[(size_t)(row + j) * ldc + col] = f2bf(e);
          rs[mf][j] += e;
        }
      }
    }
#pragma unroll
    for (int mf = 0; mf < 4; mf++)
#pragma unroll
      for (int j = 0; j < 4; j++) {
        float r = rs[mf][j];
        r += __shfl_xor(r, 1); r += __shfl_xor(r, 2);
        r += __shfl_xor(r, 4); r += __shfl_xor(r, 8);
        if (lr == 0)
          atomicAdd(&rowsum[tm * 128 + wr * 64 + mf * 16 + lq * 4 + j], r);
      }
  } else {
#pragma unroll
    for (int mf = 0; mf < 4; mf++) {
      int row = tm * 128 + wr * 64 + mf * 16 + lq * 4;
#pragma unroll
      for (int nf = 0; nf < 4; nf++) {
        int col = tn * 128 + wc * 64 + nf * 16 + lr;
        if (MODE == 2) {
#pragma unroll
          for (int j = 0; j < 4; j++)
            ((float*)C0)[(size_t)(row + j) * ldc + col] = acc[mf][nf][j] + bias[col];
        } else if (MODE == 3 && tm >= 128) {
          ushort4 o;
          o.x = f2bf(acc[mf][nf][0]); o.y = f2bf(acc[mf][nf][1]);
          o.z = f2bf(acc[mf][nf][2]); o.w = f2bf(acc[mf][nf][3]);
          *(ushort4*)(C1 + (size_t)col * 8192 + (row - 16384)) = o;
        } else {
#pragma unroll
          for (int j = 0; j < 4; j++)
            C[(size_t)(row + j) * ldc + col] = f2bf(acc[mf][nf][j]);
        }
      }
    }
  }
}

// ---------------- host ----------------
extern "C" void kernel_launch(void* const* d_in, const int* in_sizes, int n_in,
                              void* d_out, int out_size, void* d_ws, size_t ws_size,
                              hipStream_t stream) {
  const float* q  = (const float*)d_in[0];
  const float* k  = (const float*)d_in[1];
  const float* v  = (const float*)d_in[2];
  const float* lw = (const float*)d_in[3];
  const float* lb = (const float*)d_in[4];
  const float* Wq = (const float*)d_in[5];
  const float* Wp = (const float*)d_in[6];
  const float* bp = (const float*)d_in[7];

  char* ws = (char*)d_ws;
  size_t off = 0;
  auto alloc = [&](size_t b) { size_t o = off; off += (b + 255) & ~(size_t)255; return o; };
  size_t o_ln = alloc((size_t)24576 * 768 * 2);  // LN(q,k,v) bf16; later: rowsum | p0 | p1
  size_t o_pj = alloc((size_t)24576 * 768 * 2);  // qn,kn bf16 | vnT (written by qkv MODE 3)
  size_t o_wq = alloc((size_t)768 * 768 * 2);
  size_t o_wp = alloc((size_t)768 * 768 * 2);
  u16* lnbuf = (u16*)(ws + o_ln);
  u16* pj    = (u16*)(ws + o_pj);
  u16* wqb   = (u16*)(ws + o_wq);
  u16* wpb   = (u16*)(ws + o_wp);
  const size_t NS = (size_t)8192 * 768;
  float* rowsum = (float*)lnbuf;           // lnbuf dead after qkv reads it
  u16* p0 = lnbuf + NS;
  u16* p1 = lnbuf + 2 * NS;
  u16* vnT = pj + 2 * NS;                  // vn slot holds TRANSPOSED vn (qkv MODE 3)
  u16* p2 = (u16*)d_out;                   // partials 2,3 in d_out (overwritten by proj)
  u16* p3 = p2 + NS;
  size_t fixedEnd = off;
  u16* Sbuf = (u16*)(ws + fixedEnd);       // P' = exp(S*scale) bf16, 8192x8192

  const float scale = 0.03608439182435161f;  // 1/sqrt(768)

  ln_cast_kernel<<<dim3(24576), dim3(256), 0, stream>>>(q, k, v, lw, lb, lnbuf);
  cast2_f32_bf16<<<dim3(1152), dim3(256), 0, stream>>>(Wq, Wp, wqb, wpb);

  // qn/kn -> pj rows [0,16384); vn -> TRANSPOSED into vnT (MODE 3). nk=24, nTn=6, cpx=144
  gemm_fast<3><<<dim3(1152), dim3(256), 0, stream>>>(lnbuf, wqb, pj, vnT,
      768, 768, 768, 24, 6, 144, (const float*)nullptr, 1.0f, (float*)nullptr);

  zero_f32<<<dim3(32), dim3(256), 0, stream>>>(rowsum, 8192);

  // P' = exp(qn @ kn^T * scale) bf16 + rowsum atomics — gemm_fast MODE 1, 4096 blocks
  gemm_fast<1><<<dim3(4096), dim3(256), 0, stream>>>(pj, pj + NS, Sbuf, (u16*)nullptr,
      768, 768, 8192, 24, 64, 512, (const float*)nullptr, scale, rowsum);

  // attn partials = P' @ vn, 4-way split-K. nk=64, nTn=6, cpx=48
  gemm_fast<0><<<dim3(384, 4), dim3(256), 0, stream>>>(Sbuf, vnT, p0, p2,
      8192, 8192, 768, 64, 6, 48, (const float*)nullptr, 1.0f, (float*)nullptr);

  // attn_out = (p0+p1+p2+p3) / rowsum
  reduce4_scale<<<dim3(3072), dim3(256), 0, stream>>>(p0, p1, p2, p3, rowsum, p0, (int)(NS / 8));

  // out = attn_out @ W_proj^T + b_proj. nk=24, nTn=6, cpx=48
  gemm_fast<2><<<dim3(384), dim3(256), 0, stream>>>(p0, wpb, (u16*)d_out, (u16*)nullptr,
      768, 768, 768, 24, 6, 48, bp, 1.0f, (float*)nullptr);
}

// Round 16
// 339.085 us; speedup vs baseline: 1.0688x; 1.0688x over previous
//
#include <hip/hip_runtime.h>
#include <hip/hip_bf16.h>
#include <stdint.h>

typedef short bf16x8 __attribute__((ext_vector_type(8)));   // 8 bf16 in 4 VGPRs
typedef float f32x4 __attribute__((ext_vector_type(4)));
typedef unsigned short u16;
typedef u16 u16x8 __attribute__((ext_vector_type(8)));

__device__ __forceinline__ u16 f2bf(float x) {
  __hip_bfloat16 h = __float2bfloat16(x);
  return *reinterpret_cast<u16*>(&h);
}
__device__ __forceinline__ float bf2f(u16 v) {
  unsigned u = (unsigned)v << 16;
  return *reinterpret_cast<float*>(&u);
}

// async global->LDS, 16B per lane. LDS dest is wave-uniform base + lane*16 (m104/m108).
__device__ __forceinline__ void gload_lds16(const void* g, const void* lds_base) {
  __builtin_amdgcn_global_load_lds(
      (const __attribute__((address_space(1))) unsigned int*)(uintptr_t)g,
      (__attribute__((address_space(3))) unsigned int*)(uintptr_t)lds_base,
      16, 0, 0);
}

#define BAR() __builtin_amdgcn_s_barrier()

// ---------------- LayerNorm + cast to bf16 (rows of q,k,v), float4-vectorized ----------------
__global__ __launch_bounds__(256) void ln_cast_kernel(
    const float* __restrict__ q, const float* __restrict__ k, const float* __restrict__ v,
    const float* __restrict__ lw, const float* __restrict__ lb, u16* __restrict__ out) {
  int row = blockIdx.x;
  const float* x;
  if (row < 8192) x = q + (size_t)row * 768;
  else if (row < 16384) x = k + (size_t)(row - 8192) * 768;
  else x = v + (size_t)(row - 16384) * 768;
  int t = threadIdx.x;
  __shared__ float red[4];
  __shared__ float red2[4];
  float4 a = (t < 192) ? ((const float4*)x)[t] : make_float4(0.f, 0.f, 0.f, 0.f);
  float s = a.x + a.y + a.z + a.w;
  for (int o = 32; o; o >>= 1) s += __shfl_down(s, o, 64);
  if ((t & 63) == 0) red[t >> 6] = s;
  __syncthreads();
  float mean = (red[0] + red[1] + red[2]) * (1.0f / 768.0f);
  float4 d = make_float4(a.x - mean, a.y - mean, a.z - mean, a.w - mean);
  float vs = (t < 192) ? (d.x * d.x + d.y * d.y + d.z * d.z + d.w * d.w) : 0.f;
  for (int o = 32; o; o >>= 1) vs += __shfl_down(vs, o, 64);
  if ((t & 63) == 0) red2[t >> 6] = vs;
  __syncthreads();
  float var = (red2[0] + red2[1] + red2[2]) * (1.0f / 768.0f);
  float rstd = rsqrtf(var + 1e-5f);
  if (t < 192) {
    float4 wv = ((const float4*)lw)[t];
    float4 bv = ((const float4*)lb)[t];
    ushort4 o;
    o.x = f2bf(d.x * rstd * wv.x + bv.x);
    o.y = f2bf(d.y * rstd * wv.y + bv.y);
    o.z = f2bf(d.z * rstd * wv.z + bv.z);
    o.w = f2bf(d.w * rstd * wv.w + bv.w);
    ((ushort4*)(out + (size_t)row * 768))[t] = o;
  }
}

// ---------------- both weight casts in one launch ----------------
__global__ __launch_bounds__(256) void cast2_f32_bf16(
    const float* __restrict__ wa, const float* __restrict__ wb,
    u16* __restrict__ oa, u16* __restrict__ ob) {
  int i = blockIdx.x * 256 + threadIdx.x;
  const float* in = (i < 147456) ? wa : wb;
  u16* out = (i < 147456) ? oa : ob;
  int j = (i < 147456) ? i : i - 147456;
  float4 vv = ((const float4*)in)[j];
  ushort4 o;
  o.x = f2bf(vv.x); o.y = f2bf(vv.y); o.z = f2bf(vv.z); o.w = f2bf(vv.w);
  ((ushort4*)out)[j] = o;
}

// ---------------- zero fp32 buffer ----------------
__global__ __launch_bounds__(256) void zero_f32(float* __restrict__ p, int n) {
  int i = blockIdx.x * 256 + threadIdx.x;
  if (i < n) p[i] = 0.0f;
}

// ---------------- sum 4 bf16 partials, scale by 1/rowsum, write bf16 ----------------
__global__ __launch_bounds__(256) void reduce4_scale(
    const u16* __restrict__ p0, const u16* __restrict__ p1,
    const u16* __restrict__ p2, const u16* __restrict__ p3,
    const float* __restrict__ rowsum, u16* __restrict__ out, int n8) {
  int i = blockIdx.x * 256 + threadIdx.x;
  if (i < n8) {
    float inv = 1.0f / rowsum[i / 96];
    u16x8 a = ((const u16x8*)p0)[i];
    u16x8 b = ((const u16x8*)p1)[i];
    u16x8 c = ((const u16x8*)p2)[i];
    u16x8 d = ((const u16x8*)p3)[i];
    u16x8 o;
#pragma unroll
    for (int j = 0; j < 8; j++)
      o[j] = f2bf((bf2f(a[j]) + bf2f(b[j]) + bf2f(c[j]) + bf2f(d[j])) * inv);
    ((u16x8*)out)[i] = o;
  }
}

// ========== QK^T + exp, 256x256 tile, BK=32, 4-deep rotation, SINGLE barrier/phase ==========
// Proven round-12/13/14 kernel (~146us, 706 TF). Plateau notes:
//  - do NOT force waves/EU (round-10: acc spills, 8.5x slowdown)
//  - do NOT shrink to 128^2 tile (round-15: 630 TF — epilogue amortization + 1.5x FETCH)
//  - fragment pre-read infeasible: 120 VGPR + 128 AGPR = 248 of 256/wave unified budget
__global__ __launch_bounds__(512, 2) void qk_exp_256(
    const u16* __restrict__ A, const u16* __restrict__ B, u16* __restrict__ C,
    float* __restrict__ rowsum, float scale) {
  __shared__ __align__(16) u16 lds[8 * 256 * 32];  // 128 KB: A bufs 0-3 | B bufs 0-3
  int orig = blockIdx.x;               // 1024 blocks, %8==0
  int xcd = orig & 7, i = orig >> 3;
  int tm = xcd * 4 + (i & 3), tn = i >> 2;
  const int t = threadIdx.x, l = t & 63, w = t >> 6;
  const int wr = w >> 2, wc = w & 3;   // 2 x 4 wave grid
  const int lr = l & 15, lq = l >> 4;
  const int colb = lq * 16;

  f32x4 acc[8][4];
#pragma unroll
  for (int m = 0; m < 8; m++)
#pragma unroll
    for (int n = 0; n < 4; n++) acc[m][n] = (f32x4){0.f, 0.f, 0.f, 0.f};

  const size_t rA0 = (size_t)tm * 256, rB0 = (size_t)tn * 256;

  const char* gsrc[4];
  int ldsoff[4];
#pragma unroll
  for (int idx = 0; idx < 4; idx++) {
    const u16* src = (idx < 2) ? A : B;
    size_t r0 = (idx < 2) ? rA0 : rB0;
    int p = idx & 1;
    int x = p * 8192 + t * 16;
    int r = x >> 6;
    int cb = (x & 63) ^ (((r >> 1) & 3) << 4);
    gsrc[idx] = (const char*)(src + (r0 + r) * 768) + cb;
    ldsoff[idx] = ((idx < 2) ? 0 : 65536) + p * 8192 + w * 1024;
  }
  int offA[2][4], offB[4];
#pragma unroll
  for (int mh = 0; mh < 2; mh++)
#pragma unroll
    for (int mf = 0; mf < 4; mf++) {
      int row = wr * 128 + (mh * 4 + mf) * 16 + lr;
      int x = row * 64 + colb;
      offA[mh][mf] = x ^ (((row >> 1) & 3) << 4);
    }
#pragma unroll
  for (int nf = 0; nf < 4; nf++) {
    int row = wc * 64 + nf * 16 + lr;
    int x = row * 64 + colb;
    offB[nf] = 65536 + (x ^ (((row >> 1) & 3) << 4));
  }

#define SCALL(BUF, TT, IDX)                                                  \
  gload_lds16(gsrc[IDX] + (size_t)(TT) * 64,                                 \
              (const char*)lds + (BUF) * 16384 + ldsoff[IDX])

  auto LOADA = [&](bf16x8 (&aF)[4], int b, int mh) {
#pragma unroll
    for (int mf = 0; mf < 4; mf++)
      aF[mf] = *(const bf16x8*)((const char*)lds + b * 16384 + offA[mh][mf]);
  };
  auto LOADB = [&](bf16x8 (&bF)[4], int b) {
#pragma unroll
    for (int nf = 0; nf < 4; nf++)
      bF[nf] = *(const bf16x8*)((const char*)lds + b * 16384 + offB[nf]);
  };
  auto MM32 = [&](bf16x8 (&aF)[4], bf16x8 (&aG)[4], bf16x8 (&bF)[4]) {
    __builtin_amdgcn_s_setprio(1);
#pragma unroll
    for (int mf = 0; mf < 4; mf++)
#pragma unroll
      for (int nf = 0; nf < 4; nf++)
        acc[mf][nf] = __builtin_amdgcn_mfma_f32_16x16x32_bf16(
            aF[mf], bF[nf], acc[mf][nf], 0, 0, 0);
#pragma unroll
    for (int mf = 0; mf < 4; mf++)
#pragma unroll
      for (int nf = 0; nf < 4; nf++)
        acc[4 + mf][nf] = __builtin_amdgcn_mfma_f32_16x16x32_bf16(
            aG[mf], bF[nf], acc[4 + mf][nf], 0, 0, 0);
    __builtin_amdgcn_s_setprio(0);
  };

#define PHASE(CUR, SBUF, STAGET, DOSTAGE, VMN)                               \
  do {                                                                       \
    bf16x8 aF[4], aG[4], bF[4];                                              \
    LOADA(aF, CUR, 0);                                                       \
    LOADA(aG, CUR, 1);                                                       \
    LOADB(bF, CUR);                                                          \
    if (DOSTAGE) {                                                           \
      SCALL(SBUF, STAGET, 0); SCALL(SBUF, STAGET, 1);                        \
      SCALL(SBUF, STAGET, 2); SCALL(SBUF, STAGET, 3);                        \
    }                                                                        \
    MM32(aF, aG, bF);                                                        \
    if ((VMN) == 8) asm volatile("s_waitcnt vmcnt(8)" ::: "memory");         \
    else if ((VMN) == 4) asm volatile("s_waitcnt vmcnt(4)" ::: "memory");    \
    else if ((VMN) == 0) asm volatile("s_waitcnt vmcnt(0)" ::: "memory");    \
    BAR();                                                                   \
  } while (0)

  SCALL(0, 0, 0); SCALL(0, 0, 1); SCALL(0, 0, 2); SCALL(0, 0, 3);
  SCALL(1, 1, 0); SCALL(1, 1, 1); SCALL(1, 1, 2); SCALL(1, 1, 3);
  SCALL(2, 2, 0); SCALL(2, 2, 1); SCALL(2, 2, 2); SCALL(2, 2, 3);
  asm volatile("s_waitcnt vmcnt(8)" ::: "memory");
  BAR();

  for (int Tb = 0; Tb < 20; Tb += 4) {
    PHASE(0, 3, Tb + 3, 1, 8);
    PHASE(1, 0, Tb + 4, 1, 8);
    PHASE(2, 1, Tb + 5, 1, 8);
    PHASE(3, 2, Tb + 6, 1, 8);
  }
  PHASE(0, 3, 23, 1, 8);
  PHASE(1, 0, 0, 0, 4);
  PHASE(2, 0, 0, 0, 0);
  PHASE(3, 0, 0, 0, -1);

#undef PHASE
#undef SCALL

  float rs[8][4];
#pragma unroll
  for (int m = 0; m < 8; m++)
#pragma unroll
    for (int j = 0; j < 4; j++) rs[m][j] = 0.0f;
  const size_t rowBase = rA0 + (size_t)wr * 128;
  const int colBase = tn * 256 + wc * 64;
#pragma unroll
  for (int mi = 0; mi < 8; mi++) {
    size_t row0 = rowBase + mi * 16 + lq * 4;
#pragma unroll
    for (int nf = 0; nf < 4; nf++) {
      int col = colBase + nf * 16 + lr;
#pragma unroll
      for (int j = 0; j < 4; j++) {
        float e = __expf(acc[mi][nf][j] * scale);
        C[(row0 + j) * 8192 + col] = f2bf(e);
        rs[mi][j] += e;
      }
    }
  }
#pragma unroll
  for (int mi = 0; mi < 8; mi++)
#pragma unroll
    for (int j = 0; j < 4; j++) {
      float r = rs[mi][j];
      r += __shfl_xor(r, 1); r += __shfl_xor(r, 2);
      r += __shfl_xor(r, 4); r += __shfl_xor(r, 8);
      if (lr == 0) atomicAdd(&rowsum[rowBase + mi * 16 + lq * 4 + j], r);
    }
}

// ========== unified fast bt-GEMM: 128x128 tile, BK=32, 4-rot, stage-ahead-3, vmcnt(8) ==========
// Round-12/13-proven schedule (single barrier/phase, counted vmcnt, involution swizzle,
// 64KB LDS -> 2 blocks/CU). 256 thr = 4 waves (2x2 of 64x64). Runtime nk = K/32.
// MODE 0: PV partial — K-offset z*2048, C = partial bufs, bf16 out
// MODE 2: f32 out + bias[col]
// MODE 3: qkv — tiles tm>=128 (vn rows) write TRANSPOSED into C1 as vnT[col][row-16384]
template <int MODE>
__global__ __launch_bounds__(256, 2) void gemm_fast(
    const u16* __restrict__ A, const u16* __restrict__ B,
    u16* __restrict__ C0, u16* __restrict__ C1,
    int lda, int ldb, int ldc, int nk, int nTn, int cpx,
    const float* __restrict__ bias) {
  __shared__ __align__(16) u16 lds[4 * 8192];  // 64 KB: A bufs 0-3 (32KB) | B bufs 0-3 (32KB)
  const int z = blockIdx.y;
  const int koff = (MODE == 0) ? (z << 11) : 0;
  u16* C = C0;
  if (MODE == 0) C = (z < 2) ? C0 + (size_t)z * 6291456 : C1 + (size_t)(z - 2) * 6291456;
  int orig = blockIdx.x;                       // gridDim.x % 8 == 0
  int wg = (orig & 7) * cpx + (orig >> 3);
  int tm = wg / nTn, tn = wg % nTn;
  const int t = threadIdx.x, l = t & 63, w = t >> 6;
  const int wr = w >> 1, wc = w & 1;           // 2 x 2 wave grid
  const int lr = l & 15, lq = l >> 4;
  const int colb = lq * 16;

  f32x4 acc[4][4];
#pragma unroll
  for (int m = 0; m < 4; m++)
#pragma unroll
    for (int n = 0; n < 4; n++) acc[m][n] = (f32x4){0.f, 0.f, 0.f, 0.f};

  const size_t rA0 = (size_t)tm * 128, rB0 = (size_t)tn * 128;

  // hoisted addressing (idx: 0,1 = A row-halves; 2,3 = B row-halves)
  const char* gsrc[4];
  int ldsoff[4];
#pragma unroll
  for (int idx = 0; idx < 4; idx++) {
    const u16* src = (idx < 2) ? A : B;
    size_t r0 = (idx < 2) ? rA0 : rB0;
    int ld = (idx < 2) ? lda : ldb;
    int p = idx & 1;
    int x = p * 4096 + t * 16;                  // byte offset in 8KB half
    int r = x >> 6;                             // row 0..127
    int cb = (x & 63) ^ (((r >> 1) & 3) << 4);  // pre-swizzled source byte col
    gsrc[idx] = (const char*)(src + (r0 + r) * (size_t)ld + koff) + cb;
    ldsoff[idx] = ((idx < 2) ? 0 : 32768) + p * 4096 + w * 1024;
  }
  int offA[4], offB[4];
#pragma unroll
  for (int mf = 0; mf < 4; mf++) {
    int row = wr * 64 + mf * 16 + lr;
    int x = row * 64 + colb;
    offA[mf] = x ^ (((row >> 1) & 3) << 4);
  }
#pragma unroll
  for (int nf = 0; nf < 4; nf++) {
    int row = wc * 64 + nf * 16 + lr;
    int x = row * 64 + colb;
    offB[nf] = 32768 + (x ^ (((row >> 1) & 3) << 4));
  }

#define GSCALL(BUF, TT, IDX)                                                 \
  gload_lds16(gsrc[IDX] + (size_t)(TT) * 64,                                 \
              (const char*)lds + (BUF) * 8192 + ldsoff[IDX])

  // prologue: stage tiles 0,1,2; wait tile 0 (8 in flight); barrier
  GSCALL(0, 0, 0); GSCALL(0, 0, 1); GSCALL(0, 0, 2); GSCALL(0, 0, 3);
  GSCALL(1, 1, 0); GSCALL(1, 1, 1); GSCALL(1, 1, 2); GSCALL(1, 1, 3);
  GSCALL(2, 2, 0); GSCALL(2, 2, 1); GSCALL(2, 2, 2); GSCALL(2, 2, 3);
  asm volatile("s_waitcnt vmcnt(8)" ::: "memory");
  BAR();

  for (int T = 0; T < nk; T++) {
    const int cur = T & 3;
    bf16x8 aF[4], bF[4];
#pragma unroll
    for (int mf = 0; mf < 4; mf++)
      aF[mf] = *(const bf16x8*)((const char*)lds + cur * 8192 + offA[mf]);
#pragma unroll
    for (int nf = 0; nf < 4; nf++)
      bF[nf] = *(const bf16x8*)((const char*)lds + cur * 8192 + offB[nf]);
    if (T + 3 < nk) {
      const int nb = (T + 3) & 3;
      GSCALL(nb, T + 3, 0); GSCALL(nb, T + 3, 1);
      GSCALL(nb, T + 3, 2); GSCALL(nb, T + 3, 3);
    }
    __builtin_amdgcn_s_setprio(1);
#pragma unroll
    for (int mf = 0; mf < 4; mf++)
#pragma unroll
      for (int nf = 0; nf < 4; nf++)
        acc[mf][nf] = __builtin_amdgcn_mfma_f32_16x16x32_bf16(
            aF[mf], bF[nf], acc[mf][nf], 0, 0, 0);
    __builtin_amdgcn_s_setprio(0);
    if (T < nk - 3)       asm volatile("s_waitcnt vmcnt(8)" ::: "memory");
    else if (T == nk - 3) asm volatile("s_waitcnt vmcnt(4)" ::: "memory");
    else if (T == nk - 2) asm volatile("s_waitcnt vmcnt(0)" ::: "memory");
    BAR();
  }
#undef GSCALL

  // epilogue (C/D layout col=lane&15, row=(lane>>4)*4+j)
#pragma unroll
  for (int mf = 0; mf < 4; mf++) {
    int row = tm * 128 + wr * 64 + mf * 16 + lq * 4;
#pragma unroll
    for (int nf = 0; nf < 4; nf++) {
      int col = tn * 128 + wc * 64 + nf * 16 + lr;
      if (MODE == 2) {
#pragma unroll
        for (int j = 0; j < 4; j++)
          ((float*)C0)[(size_t)(row + j) * ldc + col] = acc[mf][nf][j] + bias[col];
      } else if (MODE == 3 && tm >= 128) {
        ushort4 o;
        o.x = f2bf(acc[mf][nf][0]); o.y = f2bf(acc[mf][nf][1]);
        o.z = f2bf(acc[mf][nf][2]); o.w = f2bf(acc[mf][nf][3]);
        *(ushort4*)(C1 + (size_t)col * 8192 + (row - 16384)) = o;
      } else {
#pragma unroll
        for (int j = 0; j < 4; j++)
          C[(size_t)(row + j) * ldc + col] = f2bf(acc[mf][nf][j]);
      }
    }
  }
}

// ---------------- host ----------------
extern "C" void kernel_launch(void* const* d_in, const int* in_sizes, int n_in,
                              void* d_out, int out_size, void* d_ws, size_t ws_size,
                              hipStream_t stream) {
  const float* q  = (const float*)d_in[0];
  const float* k  = (const float*)d_in[1];
  const float* v  = (const float*)d_in[2];
  const float* lw = (const float*)d_in[3];
  const float* lb = (const float*)d_in[4];
  const float* Wq = (const float*)d_in[5];
  const float* Wp = (const float*)d_in[6];
  const float* bp = (const float*)d_in[7];

  char* ws = (char*)d_ws;
  size_t off = 0;
  auto alloc = [&](size_t b) { size_t o = off; off += (b + 255) & ~(size_t)255; return o; };
  size_t o_ln = alloc((size_t)24576 * 768 * 2);  // LN(q,k,v) bf16; later: rowsum | p0 | p1
  size_t o_pj = alloc((size_t)24576 * 768 * 2);  // qn,kn bf16 | vnT (written by qkv MODE 3)
  size_t o_wq = alloc((size_t)768 * 768 * 2);
  size_t o_wp = alloc((size_t)768 * 768 * 2);
  u16* lnbuf = (u16*)(ws + o_ln);
  u16* pj    = (u16*)(ws + o_pj);
  u16* wqb   = (u16*)(ws + o_wq);
  u16* wpb   = (u16*)(ws + o_wp);
  const size_t NS = (size_t)8192 * 768;
  float* rowsum = (float*)lnbuf;           // lnbuf dead after qkv reads it (zero AFTER qkv)
  u16* p0 = lnbuf + NS;
  u16* p1 = lnbuf + 2 * NS;
  u16* vnT = pj + 2 * NS;                  // vn slot holds TRANSPOSED vn (qkv MODE 3)
  u16* p2 = (u16*)d_out;                   // partials 2,3 in d_out (overwritten by proj)
  u16* p3 = p2 + NS;
  size_t fixedEnd = off;
  u16* Sbuf = (u16*)(ws + fixedEnd);       // P' = exp(S*scale) bf16, 8192x8192

  const float scale = 0.03608439182435161f;  // 1/sqrt(768)

  ln_cast_kernel<<<dim3(24576), dim3(256), 0, stream>>>(q, k, v, lw, lb, lnbuf);
  cast2_f32_bf16<<<dim3(1152), dim3(256), 0, stream>>>(Wq, Wp, wqb, wpb);

  // qn/kn -> pj rows [0,16384); vn -> TRANSPOSED into vnT (MODE 3). nk=24, nTn=6, cpx=144
  gemm_fast<3><<<dim3(1152), dim3(256), 0, stream>>>(lnbuf, wqb, pj, vnT,
      768, 768, 768, 24, 6, 144, (const float*)nullptr);

  zero_f32<<<dim3(32), dim3(256), 0, stream>>>(rowsum, 8192);

  // P' = exp(qn @ kn^T * scale), rowsum via atomics — proven 256^2 single-barrier kernel
  qk_exp_256<<<dim3(1024), dim3(512), 0, stream>>>(pj, pj + NS, Sbuf, rowsum, scale);

  // attn partials = P' @ vn, 4-way split-K. nk=64, nTn=6, cpx=48
  gemm_fast<0><<<dim3(384, 4), dim3(256), 0, stream>>>(Sbuf, vnT, p0, p2,
      8192, 8192, 768, 64, 6, 48, (const float*)nullptr);

  // attn_out = (p0+p1+p2+p3) / rowsum
  reduce4_scale<<<dim3(3072), dim3(256), 0, stream>>>(p0, p1, p2, p3, rowsum, p0, (int)(NS / 8));

  // out = attn_out @ W_proj^T + b_proj. nk=24, nTn=6, cpx=48
  gemm_fast<2><<<dim3(384), dim3(256), 0, stream>>>(p0, wpb, (u16*)d_out, (u16*)nullptr,
      768, 768, 768, 24, 6, 48, bp);
}